// Round 1
// baseline (6737.485 us; speedup 1.0000x reference)
//
#include <hip/hip_runtime.h>
#include <hip/hip_bf16.h>
#include <math.h>

#define MINN 1e-7f

// Problem dims (fixed by setup_inputs)
#define BB 64
#define SS 128
#define DD 768
#define HH 768
#define NCOL 3840            // 768 (W_d) + 4*768 (gates)
#define NWG_GEMM 240         // NCOL/16

static const size_t BSH = (size_t)BB * SS * HH;

__device__ __forceinline__ float artanh_c(float x) {
  x = fminf(fmaxf(x, -1.0f + 1e-6f), 1.0f - 1e-6f);
  return atanhf(x);
}
__device__ __forceinline__ float tan_k_(float x, float sq) { return tanhf(sq * x) / sq; }
__device__ __forceinline__ float artan_k_(float x, float sq) { return artanh_c(sq * x) / sq; }

template <int N>
__device__ __forceinline__ void block_reduce_sum(float* v, float* red) {
#pragma unroll
  for (int m = 1; m < 64; m <<= 1) {
#pragma unroll
    for (int i = 0; i < N; ++i) v[i] += __shfl_xor(v[i], m, 64);
  }
  int wid = threadIdx.x >> 6;
  int lane = threadIdx.x & 63;
  if (lane == 0) {
#pragma unroll
    for (int i = 0; i < N; ++i) red[wid * N + i] = v[i];
  }
  __syncthreads();
#pragma unroll
  for (int i = 0; i < N; ++i) v[i] = red[i] + red[N + i] + red[2 * N + i] + red[3 * N + i];
  __syncthreads();
}

// Build combined weight matrix, chunked: CW[j][k][cc] = weight(k, col=j*16+cc)
// col<768: W_d[col][k]; else g=(col-768)/768, j2=(col-768)%768: W_all[j2][g*768+k]
__global__ __launch_bounds__(256) void k_build_cw(const float* __restrict__ W_all,
                                                  const float* __restrict__ W_d,
                                                  float* __restrict__ CW) {
  int j = blockIdx.x;
  float* dst = CW + (size_t)j * 12288;
  for (int idx = threadIdx.x; idx < 12288; idx += 256) {
    int k = idx >> 4;
    int cc = idx & 15;
    int col = j * 16 + cc;
    float v;
    if (col < 768) {
      v = W_d[col * 768 + k];
    } else {
      int jm = col - 768;
      int g = jm / 768;
      int j2 = jm - g * 768;
      v = W_all[j2 * 3072 + g * 768 + k];
    }
    dst[idx] = v;
  }
}

__global__ __launch_bounds__(256) void k_init_state(const float* __restrict__ h0,
                                                    const float* __restrict__ c0,
                                                    float* __restrict__ ccR, float* __restrict__ hR,
                                                    float* __restrict__ ccT, float* __restrict__ hT) {
  int r = blockIdx.x;
#pragma unroll
  for (int p = 0; p < 3; ++p) {
    int j = threadIdx.x + 256 * p;
    float cv = c0[r * 768 + j];
    float hv = h0[r * 768 + j];
    ccR[r * 768 + j] = cv;
    hR[r * 768 + j] = hv;
    ccT[j * 64 + r] = cv;
    hT[j * 64 + r] = hv;
  }
}

__global__ __launch_bounds__(256) void k_xnorm(const float* __restrict__ X,
                                               float* __restrict__ XN) {
  __shared__ float red[4];
  int r = blockIdx.x;
  float s = 0.f;
#pragma unroll
  for (int p = 0; p < 3; ++p) {
    float v = X[(size_t)r * 768 + threadIdx.x + 256 * p];
    s += v * v;
  }
#pragma unroll
  for (int m = 1; m < 64; m <<= 1) s += __shfl_xor(s, m, 64);
  if ((threadIdx.x & 63) == 0) red[threadIdx.x >> 6] = s;
  __syncthreads();
  if (threadIdx.x == 0) XN[r] = fmaxf(sqrtf(red[0] + red[1] + red[2] + red[3]), MINN);
}

// C[i][m] = sum_k X[i][k] * U[m][k];  M=8192, N=3072, K=768. Output bf16.
__global__ __launch_bounds__(256) void k_gemm_xu(const float* __restrict__ X,
                                                 const float* __restrict__ U,
                                                 __hip_bfloat16* __restrict__ OUT) {
  __shared__ float As[64][17];
  __shared__ float Bs[64][17];
  int tid = threadIdx.x;
  int lr = tid >> 2;
  int lk = (tid & 3) * 4;
  int tm = tid & 15;
  int ti = tid >> 4;
  const float* xr = X + (size_t)(blockIdx.x * 64 + lr) * 768 + lk;
  const float* ur = U + (size_t)(blockIdx.y * 64 + lr) * 768 + lk;
  float acc[4][4];
#pragma unroll
  for (int a = 0; a < 4; ++a)
#pragma unroll
    for (int b = 0; b < 4; ++b) acc[a][b] = 0.f;

  for (int kt = 0; kt < 768; kt += 16) {
    float4 a = *(const float4*)(xr + kt);
    float4 b = *(const float4*)(ur + kt);
    As[lr][lk + 0] = a.x; As[lr][lk + 1] = a.y; As[lr][lk + 2] = a.z; As[lr][lk + 3] = a.w;
    Bs[lr][lk + 0] = b.x; Bs[lr][lk + 1] = b.y; Bs[lr][lk + 2] = b.z; Bs[lr][lk + 3] = b.w;
    __syncthreads();
#pragma unroll
    for (int k = 0; k < 16; ++k) {
      float av[4], bv[4];
#pragma unroll
      for (int q = 0; q < 4; ++q) {
        av[q] = As[ti * 4 + q][k];
        bv[q] = Bs[tm * 4 + q][k];
      }
#pragma unroll
      for (int rr = 0; rr < 4; ++rr)
#pragma unroll
        for (int c2 = 0; c2 < 4; ++c2) acc[rr][c2] += av[rr] * bv[c2];
    }
    __syncthreads();
  }
#pragma unroll
  for (int rr = 0; rr < 4; ++rr)
#pragma unroll
    for (int c2 = 0; c2 < 4; ++c2)
      OUT[(size_t)(blockIdx.x * 64 + ti * 4 + rr) * 3072 + blockIdx.y * 64 + tm * 4 + c2] =
          __float2bfloat16(acc[rr][c2]);
}

// Per-step GEMM: GOUT[row][col] = sum_k state[k][row] * CW[k][col]
// cols 0..767 use ccT; cols 768..3839 use hT. 240 WGs x 16 cols.
__global__ __launch_bounds__(256) void k_step_gemm(const float* __restrict__ CW,
                                                   const float* __restrict__ ccT,
                                                   const float* __restrict__ hT,
                                                   float* __restrict__ GOUT) {
  __shared__ float Wl[12288];  // [k][16] chunk, 48 KB
  int j = blockIdx.x;
  int tid = threadIdx.x;
  const float4* s4 = (const float4*)(CW + (size_t)j * 12288);
  float4* d4 = (float4*)Wl;
#pragma unroll
  for (int it = 0; it < 12; ++it) d4[tid + 256 * it] = s4[tid + 256 * it];
  __syncthreads();
  const float* src = (j < 48) ? ccT : hT;
  int c = tid & 15;
  int rg = tid >> 4;
  const float* sp = src + 4 * rg;
  float a0 = 0.f, a1 = 0.f, a2 = 0.f, a3 = 0.f;
#pragma unroll 8
  for (int k = 0; k < 768; ++k) {
    float4 s = *(const float4*)(sp + (size_t)k * 64);
    float w = Wl[k * 16 + c];
    a0 += s.x * w;
    a1 += s.y * w;
    a2 += s.z * w;
    a3 += s.w * w;
  }
  int col = j * 16 + c;
  GOUT[(4 * rg + 0) * NCOL + col] = a0;
  GOUT[(4 * rg + 1) * NCOL + col] = a1;
  GOUT[(4 * rg + 2) * NCOL + col] = a2;
  GOUT[(4 * rg + 3) * NCOL + col] = a3;
}

// Per-step pointwise hyperbolic math; one WG per batch row.
__global__ __launch_bounds__(256) void k_step_pw(
    const float* __restrict__ GOUT, const __hip_bfloat16* __restrict__ UG,
    const float* __restrict__ XN, const float* __restrict__ TS,
    const float* __restrict__ kptr, float* __restrict__ ccR, float* __restrict__ hR,
    float* __restrict__ ccT, float* __restrict__ hT, float* __restrict__ out, int t) {
  __shared__ float red[64];
  int r = blockIdx.x;
  int tid = threadIdx.x;
  float kk = kptr[0];
  float sq = sqrtf(-kk);
  const float* grow = GOUT + r * NCOL;
  int i = r * SS + t;
  const __hip_bfloat16* urow = UG + (size_t)i * 3072;

  float cc[3], h[3], mv[3], gh[4][3], mx[4][3];
#pragma unroll
  for (int p = 0; p < 3; ++p) {
    int j = tid + 256 * p;
    cc[p] = ccR[r * 768 + j];
    h[p] = hR[r * 768 + j];
    mv[p] = grow[j];
#pragma unroll
    for (int g = 0; g < 4; ++g) {
      gh[g][p] = grow[768 + g * 768 + j];
      mx[g][p] = __bfloat162float(urow[g * 768 + j]);
    }
  }

  // batch1: {c2, h2, mvn2, |gh_g|^2 x4, gh_g.mx_g x4, |mx_g|^2 x4}
  float sv[15];
#pragma unroll
  for (int q = 0; q < 15; ++q) sv[q] = 0.f;
#pragma unroll
  for (int p = 0; p < 3; ++p) {
    sv[0] += cc[p] * cc[p];
    sv[1] += h[p] * h[p];
    sv[2] += mv[p] * mv[p];
#pragma unroll
    for (int g = 0; g < 4; ++g) {
      sv[3 + g] += gh[g][p] * gh[g][p];
      sv[7 + g] += gh[g][p] * mx[g][p];
      sv[11 + g] += mx[g][p] * mx[g][p];
    }
  }
  block_reduce_sum<15>(sv, red);
  float c2 = sv[0], h2 = sv[1], mvn2 = sv[2];
  float xn_c = fmaxf(sqrtf(c2), MINN);
  float xn_h = fmaxf(sqrtf(h2), MINN);
  float mxn_d = fmaxf(sqrtf(mvn2), MINN);

  // W_d path: l = logmap0(mobius_matvec(W_d, cc)), th = tanh(l)
  float r_d = (mxn_d / xn_c) * artan_k_(xn_c, sq);
  float twd = tan_k_(r_d, sq);
  float wdsc = twd / mxn_d;
  float yn_d = fmaxf(fabsf(twd), MINN);
  float lsc = (artan_k_(yn_d, sq) / yn_d) * wdsc;
  float th[3];
#pragma unroll
  for (int p = 0; p < 3; ++p) th[p] = tanhf(lsc * mv[p]);

  // gates: sigmoid(logmap0(mobius_add(Wmv_g, Umv_g)))
  float uxn = XN[i];
  float ak_h = artan_k_(xn_h, sq);
  float ak_u = artan_k_(uxn, sq);
  float cAg[4], cBg[4], pscg[4];
#pragma unroll
  for (int g = 0; g < 4; ++g) {
    float ghn = fmaxf(sqrtf(sv[3 + g]), MINN);
    float tg = tan_k_((ghn / xn_h) * ak_h, sq);
    float wsc = tg / ghn;
    float w2 = tg * tg;
    float umxn = fmaxf(sqrtf(sv[11 + g]), MINN);
    float us = tan_k_((umxn / uxn) * ak_u, sq) / umxn;
    float u2 = us * us * sv[11 + g];
    float xy = wsc * us * sv[7 + g];
    float den = fmaxf(1.f - 2.f * kk * xy + kk * kk * w2 * u2, MINN);
    float a = (1.f - 2.f * kk * xy - kk * u2) / den;
    float b = (1.f + kk * w2) / den;
    float y2s = fmaxf(a * a * w2 + 2.f * a * b * xy + b * b * u2, 0.f);
    float yn = fmaxf(sqrtf(y2s), MINN);
    pscg[g] = artan_k_(yn, sq) / yn;
    cAg[g] = a * wsc;
    cBg[g] = b * us;
  }
  float gate[4][3];
#pragma unroll
  for (int g = 0; g < 4; ++g)
#pragma unroll
    for (int p = 0; p < 3; ++p)
      gate[g][p] = 1.f / (1.f + expf(-pscg[g] * (cAg[g] * gh[g][p] + cBg[g] * mx[g][p])));

  // batch2: {|th|^2, th.cc}
  float s2v[2] = {0.f, 0.f};
#pragma unroll
  for (int p = 0; p < 3; ++p) {
    s2v[0] += th[p] * th[p];
    s2v[1] += th[p] * cc[p];
  }
  block_reduce_sum<2>(s2v, red);
  float un = fmaxf(sqrtf(s2v[0]), MINN);
  float esc = tan_k_(un, sq) / un;
  float cs1[3];
#pragma unroll
  for (int p = 0; p < 3; ++p) cs1[p] = esc * th[p];
  float d1 = esc * s2v[1];          // cs1 . cc
  float s1sq = esc * esc * s2v[0];  // |cs1|^2

  // c_s2 = mobius_pmul(c_s1, t_exp) = s2s * cs1
  float tv = TS[r * SS + t];
  float xnt = fmaxf(sqrtf(768.f * tv * tv), MINN);
  float wxn_t = fmaxf(fabsf(tv) * sqrtf(s1sq), MINN);
  float s2s = tan_k_((wxn_t / xnt) * artan_k_(xnt, sq), sq) / wxn_t * tv;
  float s2sq = s2s * s2s * s1sq;

  // c_l = mobius_add(-cs1, cc) = pcl*cs1 + qcl*cc
  float den_l = fmaxf(1.f + 2.f * kk * d1 + kk * kk * s1sq * c2, MINN);
  float al = (1.f + 2.f * kk * d1 - kk * c2) / den_l;
  float bl = (1.f + kk * s1sq) / den_l;
  float pcl = -al, qcl = bl;

  // c_adj = mobius_add(c_l, c_s2) = g1c*cs1 + g2c*cc
  float xy2 = s2s * (pcl * s1sq + qcl * d1);
  float x2b = fmaxf(pcl * pcl * s1sq + 2.f * pcl * qcl * d1 + qcl * qcl * c2, 0.f);
  float y2b = s2sq;
  float den2 = fmaxf(1.f - 2.f * kk * xy2 + kk * kk * x2b * y2b, MINN);
  float a2 = (1.f - 2.f * kk * xy2 - kk * y2b) / den2;
  float b2 = (1.f + kk * x2b) / den2;
  float g1c = a2 * pcl + b2 * s2s;
  float g2c = a2 * qcl;
  float cadj[3];
#pragma unroll
  for (int p = 0; p < 3; ++p) cadj[p] = g1c * cs1[p] + g2c * cc[p];
  float adjsq = fmaxf(g1c * g1c * s1sq + 2.f * g1c * g2c * d1 + g2c * g2c * c2, 0.f);

  // P_i = pmul(i, c_tmp), P_f = pmul(f, c_adj), new_c = madd(P_i, P_f)
  float wxi[3], wxf[3];
#pragma unroll
  for (int p = 0; p < 3; ++p) {
    wxi[p] = gate[1][p] * gate[3][p];
    wxf[p] = gate[0][p] * cadj[p];
  }
  float s3v[4] = {0.f, 0.f, 0.f, 0.f};
#pragma unroll
  for (int p = 0; p < 3; ++p) {
    s3v[0] += gate[3][p] * gate[3][p];
    s3v[1] += wxi[p] * wxi[p];
    s3v[2] += wxf[p] * wxf[p];
    s3v[3] += wxi[p] * wxf[p];
  }
  block_reduce_sum<4>(s3v, red);
  float xnct = fmaxf(sqrtf(s3v[0]), MINN);
  float wxni = fmaxf(sqrtf(s3v[1]), MINN);
  float psi = tan_k_((wxni / xnct) * artan_k_(xnct, sq), sq) / wxni;
  float pi2 = psi * psi * s3v[1];
  float xnadj = fmaxf(sqrtf(adjsq), MINN);
  float wxnf = fmaxf(sqrtf(s3v[2]), MINN);
  float psf = tan_k_((wxnf / xnadj) * artan_k_(xnadj, sq), sq) / wxnf;
  float pf2 = psf * psf * s3v[2];
  float xyp = psi * psf * s3v[3];
  float den3 = fmaxf(1.f - 2.f * kk * xyp + kk * kk * pi2 * pf2, MINN);
  float a3 = (1.f - 2.f * kk * xyp - kk * pf2) / den3;
  float b3 = (1.f + kk * pi2) / den3;
  float nc[3], tc[3];
#pragma unroll
  for (int p = 0; p < 3; ++p) {
    nc[p] = a3 * psi * wxi[p] + b3 * psf * wxf[p];
    tc[p] = tanhf(nc[p]);
  }
  float s4v[1] = {0.f};
#pragma unroll
  for (int p = 0; p < 3; ++p) s4v[0] += tc[p] * tc[p];
  block_reduce_sum<1>(s4v, red);
  float unh = fmaxf(sqrtf(s4v[0]), MINN);
  float ehs = tan_k_(unh, sq) / unh;
  float Esq = ehs * ehs * s4v[0];
  float En = fmaxf(sqrtf(Esq), MINN);
  float wxo[3];
#pragma unroll
  for (int p = 0; p < 3; ++p) wxo[p] = gate[2][p] * (ehs * tc[p]);
  float s5v[1] = {0.f};
#pragma unroll
  for (int p = 0; p < 3; ++p) s5v[0] += wxo[p] * wxo[p];
  block_reduce_sum<1>(s5v, red);
  float wxno = fmaxf(sqrtf(s5v[0]), MINN);
  float pso = tan_k_((wxno / En) * artan_k_(En, sq), sq) / wxno;

  size_t BSHc = (size_t)BB * SS * HH;
#pragma unroll
  for (int p = 0; p < 3; ++p) {
    int j = tid + 256 * p;
    out[((size_t)r * SS + t) * HH + j] = gate[2][p];  // output = o gate
    float ncv = nc[p];
    float nhv = pso * wxo[p];
    ccR[r * 768 + j] = ncv;
    ccT[j * 64 + r] = ncv;
    hR[r * 768 + j] = nhv;
    hT[j * 64 + r] = nhv;
    if (t == SS - 1) {
      out[BSHc + (size_t)r * HH + j] = nhv;               // h_last
      out[BSHc + (size_t)BB * HH + (size_t)r * HH + j] = ncv;  // c_last
    }
  }
}

extern "C" void kernel_launch(void* const* d_in, const int* in_sizes, int n_in,
                              void* d_out, int out_size, void* d_ws, size_t ws_size,
                              hipStream_t stream) {
  const float* inputs = (const float*)d_in[0];
  const float* ts = (const float*)d_in[1];
  const float* h0 = (const float*)d_in[2];
  const float* c0 = (const float*)d_in[3];
  const float* W_all = (const float*)d_in[4];
  const float* U_all = (const float*)d_in[5];
  const float* W_d = (const float*)d_in[6];
  const float* kptr = (const float*)d_in[7];
  float* ws = (float*)d_ws;
  float* out = (float*)d_out;

  size_t oCW = 0;
  size_t oCCT = oCW + (size_t)NWG_GEMM * 12288;  // 2,949,120
  size_t oHT = oCCT + 49152;
  size_t oCCR = oHT + 49152;
  size_t oHR = oCCR + 49152;
  size_t oGOUT = oHR + 49152;
  size_t oXN = oGOUT + (size_t)BB * NCOL;  // 245,760
  size_t oUG = oXN + 8192;
  __hip_bfloat16* UG = (__hip_bfloat16*)(ws + oUG);

  k_build_cw<<<NWG_GEMM, 256, 0, stream>>>(W_all, W_d, ws + oCW);
  k_init_state<<<BB, 256, 0, stream>>>(h0, c0, ws + oCCR, ws + oHR, ws + oCCT, ws + oHT);
  k_gemm_xu<<<dim3(128, 48), 256, 0, stream>>>(inputs, U_all, UG);
  k_xnorm<<<BB * SS, 256, 0, stream>>>(inputs, ws + oXN);

  for (int t = 0; t < SS; ++t) {
    k_step_gemm<<<NWG_GEMM, 256, 0, stream>>>(ws + oCW, ws + oCCT, ws + oHT, ws + oGOUT);
    k_step_pw<<<BB, 256, 0, stream>>>(ws + oGOUT, UG, ws + oXN, ts, kptr, ws + oCCR,
                                      ws + oHR, ws + oCCT, ws + oHT, out, t);
  }
}